// Round 2
// baseline (469.377 us; speedup 1.0000x reference)
//
#include <hip/hip_runtime.h>

typedef float f32x4 __attribute__((ext_vector_type(4)));

constexpr int B = 8, C = 64, H = 256, W = 256;
constexpr int HW = H * W;        // 65536
constexpr int HW4 = HW / 4;      // 16384
constexpr int W4 = W / 4;        // 64
constexpr int OUTC = 192;
constexpr int REP = 32;

// Kernel 1: channel sum S[b,h,w] = sum_c x[b,c,h,w]
// thread per float4 pixel group; 4 independent accumulator chains for ILP.
__global__ __launch_bounds__(256) void chansum_k(const float* __restrict__ x,
                                                 float* __restrict__ S) {
    int tid = blockIdx.x * 256 + threadIdx.x;      // B*HW4 = 131072 threads
    int b = tid >> 14;                             // / HW4
    int hw4 = tid & (HW4 - 1);
    const f32x4* xp = (const f32x4*)x + (size_t)b * C * HW4 + hw4;
    f32x4 a0 = 0, a1 = 0, a2 = 0, a3 = 0;
#pragma unroll
    for (int c = 0; c < C; c += 4) {
        f32x4 v0 = __builtin_nontemporal_load(xp + (size_t)(c + 0) * HW4);
        f32x4 v1 = __builtin_nontemporal_load(xp + (size_t)(c + 1) * HW4);
        f32x4 v2 = __builtin_nontemporal_load(xp + (size_t)(c + 2) * HW4);
        f32x4 v3 = __builtin_nontemporal_load(xp + (size_t)(c + 3) * HW4);
        a0 += v0; a1 += v1; a2 += v2; a3 += v3;
    }
    f32x4 s = (a0 + a1) + (a2 + a3);
    ((f32x4*)S)[(size_t)b * HW4 + hw4] = s;
}

// Kernel 2: six 3x3 stencils on S, ReLU, each replicated 32x into out.
// thread per (b, dir, h, w4); dir is wave-uniform (w4 occupies low 6 bits).
__global__ __launch_bounds__(256) void stencil_k(const float* __restrict__ S,
                                                 float* __restrict__ out) {
    int tid = blockIdx.x * 256 + threadIdx.x;      // B*6*H*W4 = 786432 threads
    int w4 = tid & (W4 - 1);
    int t = tid >> 6;
    int h = t & (H - 1);
    t >>= 8;
    int d = t % 6;
    int b = t / 6;
    int w0 = w4 << 2;

    const float* Sb = S + (size_t)b * HW;
    f32x4 cc[3];
    float ll[3], rr[3];
#pragma unroll
    for (int i = 0; i < 3; ++i) {
        int hh = h - 1 + i;
        if (hh < 0 || hh >= H) {
            cc[i] = 0; ll[i] = 0.f; rr[i] = 0.f;
        } else {
            const float* row = Sb + hh * W + w0;
            cc[i] = *(const f32x4*)row;
            ll[i] = (w0 > 0)     ? row[-1] : 0.f;
            rr[i] = (w0 + 4 < W) ? row[4]  : 0.f;
        }
    }
    f32x4 m1[3], p1[3];
#pragma unroll
    for (int i = 0; i < 3; ++i) {
        m1[i] = (f32x4){ ll[i],    cc[i][0], cc[i][1], cc[i][2] };  // shift w-1
        p1[i] = (f32x4){ cc[i][1], cc[i][2], cc[i][3], rr[i]    };  // shift w+1
    }

    f32x4 v;
    if      (d == 0) v = m1[0] + cc[1] + p1[2];                         // main diag
    else if (d == 1) v = p1[0] + cc[1] + m1[2];                         // anti diag
    else if (d == 2) v = (m1[0] + p1[0]) + cc[1] + (m1[2] + p1[2]);     // X
    else if (d == 3) v = cc[0] + (m1[1] + cc[1] + p1[1]) + cc[2];       // +
    else if (d == 4) v = m1[1] + cc[1] + p1[1];                         // horizontal
    else             v = cc[0] + cc[1] + cc[2];                         // vertical

    v = (f32x4){ fmaxf(v[0], 0.f), fmaxf(v[1], 0.f),
                 fmaxf(v[2], 0.f), fmaxf(v[3], 0.f) };

    float* op = out + (size_t)(b * OUTC + d * REP) * HW + h * W + w0;
#pragma unroll
    for (int r = 0; r < REP; ++r) {
        __builtin_nontemporal_store(v, (f32x4*)(op + (size_t)r * HW));
    }
}

extern "C" void kernel_launch(void* const* d_in, const int* in_sizes, int n_in,
                              void* d_out, int out_size, void* d_ws, size_t ws_size,
                              hipStream_t stream) {
    const float* x = (const float*)d_in[0];
    float* out = (float*)d_out;
    float* S = (float*)d_ws;   // needs B*HW*4 = 2 MiB scratch

    chansum_k<<<(B * HW4) / 256, 256, 0, stream>>>(x, S);
    stencil_k<<<(B * 6 * H * W4) / 256, 256, 0, stream>>>(S, out);
}